// Round 1
// baseline (661.245 us; speedup 1.0000x reference)
//
#include <hip/hip_runtime.h>
#include <stdint.h>

// Mamba2 chunked final-state. Collapsed math:
//   out[b,h,p,n] = sum_t exp( sum_{s>t} A[b,s,h] ) * X[b,t,h,p] * B[b,t,h,n]
// b=8, L=4096, h=32, p=n=64. C input unused.
#define LSEQ 4096
#define HDIM 32
#define PDIM 64
#define TSTRIDE 2048  // h*p stride between timesteps in X/B

// async global->LDS, 16B per lane, wave-uniform LDS base + lane*16
__device__ __forceinline__ void g2lds16(const float* gp, float* lp) {
  __builtin_amdgcn_global_load_lds(
      (const __attribute__((address_space(1))) void*)(uintptr_t)gp,
      (__attribute__((address_space(3))) void*)(uint32_t)(uintptr_t)lp,
      16, 0, 0);
}

__global__ __launch_bounds__(256, 4) void mamba_partial(
    const float* __restrict__ X, const float* __restrict__ A,
    const float* __restrict__ B, float* __restrict__ out, int G) {
  extern __shared__ float smem[];
  const int range = LSEQ / G;          // timesteps per block (512 at G=8)
  float* wlds = smem;                  // [range] suffix-decay weights
  float* Xs = smem + range;            // [64*64] staged X tile
  float* Bs = Xs + 4096;               // [64*64] staged B tile
  __shared__ float sc[4];

  const int tid = threadIdx.x;
  const int g = blockIdx.x >> 8;
  const int bh = blockIdx.x & 255;
  const int b = bh >> 5, h = bh & 31;
  const int T0 = g * range;
  const int T1 = T0 + range;
  const int lane = tid & 63, wv = tid >> 6;

  const float* Ag = A + (size_t)b * LSEQ * HDIM + h;

  // ---- tail = sum_{s >= T1} A[b,s,h]
  float ts = 0.f;
  for (int s = T1 + tid; s < LSEQ; s += 256) ts += Ag[(size_t)s * HDIM];
  Xs[tid] = ts;
  __syncthreads();
  for (int s = 128; s > 0; s >>= 1) {
    if (tid < s) Xs[tid] += Xs[tid + s];
    __syncthreads();
  }
  const float tail = Xs[0];
  __syncthreads();  // everyone has read Xs[0] before Xs is reused

  // ---- suffix weights over [T0,T1): w[t] = exp(total - incl_prefix(t) + tail)
  const int E = range >> 8;            // elements per thread (2 at G=8)
  const int s0 = T0 + tid * E;
  float seg = 0.f;
  for (int i = 0; i < E; ++i) seg += Ag[(size_t)(s0 + i) * HDIM];
  float v = seg;
#pragma unroll
  for (int d = 1; d < 64; d <<= 1) {
    float o = __shfl_up(v, d, 64);
    if (lane >= d) v += o;
  }
  if (lane == 63) sc[wv] = v;
  __syncthreads();
  float off = 0.f, total = 0.f;
  for (int j = 0; j < 4; ++j) {
    float t = sc[j];
    total += t;
    if (j < wv) off += t;
  }
  float run = off + v - seg;           // exclusive prefix for this thread's first elem
  for (int i = 0; i < E; ++i) {
    run += Ag[(size_t)(s0 + i) * HDIM];
    wlds[tid * E + i] = expf(total - run + tail);
  }
  __syncthreads();

  // ---- main loop: batches of 64 timesteps
  const float* Xg = X + (size_t)b * LSEQ * TSTRIDE + h * PDIM;
  const float* Bg = B + (size_t)b * LSEQ * TSTRIDE + h * PDIM;
  const int tl = lane >> 4;            // staging sub-row 0..3
  const int pql = (lane & 15) << 2;    // staging p-quad
  const int pr = (lane & 7) << 3;      // compute: 8 p-rows base
  const int nr = (lane >> 3) << 3;     // compute: 8 n-cols base

  float acc[8][8];
#pragma unroll
  for (int i = 0; i < 8; ++i)
#pragma unroll
    for (int j = 0; j < 8; ++j) acc[i][j] = 0.f;

  const int nb = range >> 6;
  for (int bt = 0; bt < nb; ++bt) {
    const int t0 = T0 + (bt << 6);
#pragma unroll
    for (int r = 0; r < 4; ++r) {
      const int trow = t0 + r * 16 + wv * 4 + tl;
      const int flat = r * 1024 + wv * 256;  // wave-uniform LDS float offset
      g2lds16(Xg + (size_t)trow * TSTRIDE + pql, Xs + flat);
      g2lds16(Bg + (size_t)trow * TSTRIDE + pql, Bs + flat);
    }
    __syncthreads();
    // wave wv handles timesteps [t0 + wv*16, +16)
    const float* wp = wlds + (bt << 6) + wv * 16;
    const float* xst = Xs + wv * 16 * 64;
    const float* bst = Bs + wv * 16 * 64;
#pragma unroll 2
    for (int t = 0; t < 16; ++t) {
      const float wt = wp[t];
      const float4 xa = *(const float4*)(xst + t * 64 + pr);
      const float4 xb = *(const float4*)(xst + t * 64 + pr + 4);
      const float4 ba = *(const float4*)(bst + t * 64 + nr);
      const float4 bb = *(const float4*)(bst + t * 64 + nr + 4);
      float xw[8] = {xa.x * wt, xa.y * wt, xa.z * wt, xa.w * wt,
                     xb.x * wt, xb.y * wt, xb.z * wt, xb.w * wt};
      float bv[8] = {ba.x, ba.y, ba.z, ba.w, bb.x, bb.y, bb.z, bb.w};
#pragma unroll
      for (int i = 0; i < 8; ++i)
#pragma unroll
        for (int j = 0; j < 8; ++j) acc[i][j] += xw[i] * bv[j];
    }
    __syncthreads();
  }

  // ---- cross-wave reduction (4 per-wave partials of the 64x64 tile)
  if (wv == 1) {
#pragma unroll
    for (int i = 0; i < 8; ++i) {
      *(float4*)(Xs + (pr + i) * 64 + nr) =
          make_float4(acc[i][0], acc[i][1], acc[i][2], acc[i][3]);
      *(float4*)(Xs + (pr + i) * 64 + nr + 4) =
          make_float4(acc[i][4], acc[i][5], acc[i][6], acc[i][7]);
    }
  }
  if (wv == 3) {
#pragma unroll
    for (int i = 0; i < 8; ++i) {
      *(float4*)(Bs + (pr + i) * 64 + nr) =
          make_float4(acc[i][0], acc[i][1], acc[i][2], acc[i][3]);
      *(float4*)(Bs + (pr + i) * 64 + nr + 4) =
          make_float4(acc[i][4], acc[i][5], acc[i][6], acc[i][7]);
    }
  }
  __syncthreads();
  if (wv == 0) {
#pragma unroll
    for (int i = 0; i < 8; ++i)
#pragma unroll
      for (int j = 0; j < 8; ++j) acc[i][j] += Xs[(pr + i) * 64 + nr + j];
  }
  if (wv == 2) {
#pragma unroll
    for (int i = 0; i < 8; ++i)
#pragma unroll
      for (int j = 0; j < 8; ++j) acc[i][j] += Bs[(pr + i) * 64 + nr + j];
  }
  __syncthreads();
  if (wv == 2) {
#pragma unroll
    for (int i = 0; i < 8; ++i) {
      *(float4*)(Xs + (pr + i) * 64 + nr) =
          make_float4(acc[i][0], acc[i][1], acc[i][2], acc[i][3]);
      *(float4*)(Xs + (pr + i) * 64 + nr + 4) =
          make_float4(acc[i][4], acc[i][5], acc[i][6], acc[i][7]);
    }
  }
  __syncthreads();
  if (wv == 0) {
#pragma unroll
    for (int i = 0; i < 8; ++i)
#pragma unroll
      for (int j = 0; j < 8; ++j) acc[i][j] += Xs[(pr + i) * 64 + nr + j];
    float* op = out + ((size_t)g * 256 + bh) * 4096;
#pragma unroll
    for (int i = 0; i < 8; ++i) {
      *(float4*)(op + (pr + i) * 64 + nr) =
          make_float4(acc[i][0], acc[i][1], acc[i][2], acc[i][3]);
      *(float4*)(op + (pr + i) * 64 + nr + 4) =
          make_float4(acc[i][4], acc[i][5], acc[i][6], acc[i][7]);
    }
  }
}

__global__ void reduce_k(const float4* __restrict__ ws, float4* __restrict__ out,
                         int G) {
  const int i = blockIdx.x * blockDim.x + threadIdx.x;  // 262144 float4s
  float4 s = ws[i];
  for (int g = 1; g < G; ++g) {
    const float4 v = ws[(size_t)g * 262144 + i];
    s.x += v.x;
    s.y += v.y;
    s.z += v.z;
    s.w += v.w;
  }
  out[i] = s;
}

extern "C" void kernel_launch(void* const* d_in, const int* in_sizes, int n_in,
                              void* d_out, int out_size, void* d_ws, size_t ws_size,
                              hipStream_t stream) {
  const float* X = (const float*)d_in[0];
  const float* A = (const float*)d_in[1];
  const float* B = (const float*)d_in[2];
  // d_in[3] (C) and d_in[4] (block_len) are unused by the collapsed math.
  float* out = (float*)d_out;
  float* ws = (float*)d_ws;

  int G = 8;
  while (G > 1 && ws_size < (size_t)G * 1048576u * 4u) G >>= 1;

  const dim3 blk(256);
  if (G > 1) {
    const size_t smem = (size_t)(LSEQ / G + 8192) * 4;
    mamba_partial<<<dim3(G * 256), blk, smem, stream>>>(X, A, B, ws, G);
    reduce_k<<<dim3(1024), dim3(256), 0, stream>>>((const float4*)ws,
                                                   (float4*)out, G);
  } else {
    const size_t smem = (size_t)(LSEQ + 8192) * 4;
    mamba_partial<<<dim3(256), blk, smem, stream>>>(X, A, B, out, 1);
  }
}

// Round 2
// 583.264 us; speedup vs baseline: 1.1337x; 1.1337x over previous
//
#include <hip/hip_runtime.h>
#include <stdint.h>

// Mamba2 chunked final-state. Collapsed math:
//   out[b,h,p,n] = sum_t exp( sum_{s>t} A[b,s,h] ) * X[b,t,h,p] * B[b,t,h,n]
// b=8, L=4096, h=32, p=n=64. C input unused.
//
// Key data fact: A <= 0 with |A|~0.08 avg, so w_t = exp(suffix(t)) underflows
// to 0 (in fp32, in the reference too) except for the last few hundred
// timesteps. We compute the suffix sums first, then only process
// t >= t_start where suffix(t) >= -45 (dropped terms < 1e-16 absolute).
// Correct for arbitrary A: t_start is the FIRST index passing the cut and
// everything after it is processed unconditionally.

#define LSEQ 4096
#define HDIM 32
#define TSTRIDE 2048  // h*p floats between timesteps in X/B
#define WCUT -45.0f

// async global->LDS, 16B per lane, wave-uniform LDS base + lane*16
__device__ __forceinline__ void g2lds16(const float* gp, float* lp) {
  __builtin_amdgcn_global_load_lds(
      (const __attribute__((address_space(1))) void*)(uintptr_t)gp,
      (__attribute__((address_space(3))) void*)(uint32_t)(uintptr_t)lp,
      16, 0, 0);
}

__global__ __launch_bounds__(512, 2) void mamba_fused(
    const float* __restrict__ X, const float* __restrict__ A,
    const float* __restrict__ B, float* __restrict__ out) {
  extern __shared__ float smem[];
  float* wlds = smem;          // [4096] weights
  float* Xs = smem + 4096;     // [64*64] stage X   (reused as reduce tile 0)
  float* Bs = Xs + 4096;       // [64*64] stage B   (reused as reduce tile 1)
  __shared__ float wtot[8];
  __shared__ unsigned tsmin;

  const int tid = threadIdx.x;
  const int lane = tid & 63, wv = tid >> 6;
  const int bh = blockIdx.x;
  const int b = bh >> 5, h = bh & 31;

  const float* Ag = A + (size_t)b * LSEQ * HDIM + h;

  // ---------- Phase A: suffix sums of A column, w[], t_start ----------
  if (tid == 0) tsmin = LSEQ - 1;
  float a[8];
  const int t0 = tid << 3;
#pragma unroll
  for (int j = 0; j < 8; ++j) a[j] = Ag[(size_t)(t0 + j) * HDIM];
  float s8 = 0.f;
#pragma unroll
  for (int j = 0; j < 8; ++j) s8 += a[j];
  // inclusive wave scan of per-thread sums
  float v = s8;
#pragma unroll
  for (int d = 1; d < 64; d <<= 1) {
    float o = __shfl_up(v, d, 64);
    if (lane >= d) v += o;
  }
  if (lane == 63) wtot[wv] = v;
  __syncthreads();
  float woff = 0.f, total = 0.f;
#pragma unroll
  for (int j = 0; j < 8; ++j) {
    float t = wtot[j];
    total += t;
    if (j < wv) woff += t;
  }
  float run = woff + v - s8;  // exclusive prefix entering this thread
  unsigned myfirst = LSEQ - 1;
#pragma unroll
  for (int j = 0; j < 8; ++j) {
    run += a[j];
    const float suf = total - run;  // sum_{s > t} A
    wlds[t0 + j] = expf(suf);
    if (suf >= WCUT && (unsigned)(t0 + j) < myfirst) myfirst = t0 + j;
  }
  if (myfirst < LSEQ - 1) atomicMin(&tsmin, myfirst);
  __syncthreads();
  const int tb0 = (int)tsmin & ~63;

  // ---------- Phase B: main loop over kept 64-timestep batches ----------
  const float* Xg = X + (size_t)b * LSEQ * TSTRIDE + h * 64;
  const float* Bg = B + (size_t)b * LSEQ * TSTRIDE + h * 64;
  const int lrow = lane >> 4;          // staging sub-row 0..3
  const int lcol = (lane & 15) << 2;   // staging p-quad
  const int pr = (lane & 7) << 3;      // compute: 8 p-rows base
  const int nr = (lane >> 3) << 3;     // compute: 8 n-cols base

  float acc[8][8];
#pragma unroll
  for (int i = 0; i < 8; ++i)
#pragma unroll
    for (int j = 0; j < 8; ++j) acc[i][j] = 0.f;

  for (int tb = tb0; tb < LSEQ; tb += 64) {
    __syncthreads();  // stage region free (prev batch / phase A done)
    const int r0 = wv << 3;  // this wave stages rows [r0, r0+8)
    const size_t g0 = (size_t)(tb + r0 + lrow) * TSTRIDE + lcol;
    const size_t g1 = (size_t)(tb + r0 + 4 + lrow) * TSTRIDE + lcol;
    g2lds16(Xg + g0, Xs + r0 * 64);
    g2lds16(Xg + g1, Xs + (r0 + 4) * 64);
    g2lds16(Bg + g0, Bs + r0 * 64);
    g2lds16(Bg + g1, Bs + (r0 + 4) * 64);
    __syncthreads();
    // wave wv computes timesteps [tb + wv*8, +8)
    const float* wp = wlds + tb + (wv << 3);
    const float* xst = Xs + (wv << 3) * 64;
    const float* bst = Bs + (wv << 3) * 64;
#pragma unroll
    for (int t = 0; t < 8; ++t) {
      const float wt = wp[t];
      const float4 xa = *(const float4*)(xst + t * 64 + pr);
      const float4 xb = *(const float4*)(xst + t * 64 + pr + 4);
      const float4 ba = *(const float4*)(bst + t * 64 + nr);
      const float4 bb = *(const float4*)(bst + t * 64 + nr + 4);
      float xw[8] = {xa.x * wt, xa.y * wt, xa.z * wt, xa.w * wt,
                     xb.x * wt, xb.y * wt, xb.z * wt, xb.w * wt};
      float bv[8] = {ba.x, ba.y, ba.z, ba.w, bb.x, bb.y, bb.z, bb.w};
#pragma unroll
      for (int i = 0; i < 8; ++i)
#pragma unroll
        for (int j = 0; j < 8; ++j) acc[i][j] += xw[i] * bv[j];
    }
  }
  __syncthreads();  // main loop LDS reads done; stage region -> reduce tiles

  // ---------- Phase C: reduce 8 per-wave partial tiles ----------
  float* T0 = Xs;  // 16 KB tile
  float* T1 = Bs;  // 16 KB tile
  auto wr = [&](float* T) {
#pragma unroll
    for (int i = 0; i < 8; ++i) {
      *(float4*)(T + (pr + i) * 64 + nr) =
          make_float4(acc[i][0], acc[i][1], acc[i][2], acc[i][3]);
      *(float4*)(T + (pr + i) * 64 + nr + 4) =
          make_float4(acc[i][4], acc[i][5], acc[i][6], acc[i][7]);
    }
  };
  auto ad = [&](const float* T) {
#pragma unroll
    for (int i = 0; i < 8; ++i)
#pragma unroll
      for (int j = 0; j < 8; ++j) acc[i][j] += T[(pr + i) * 64 + nr + j];
  };

  if (wv == 4) wr(T0);
  if (wv == 5) wr(T1);
  __syncthreads();
  if (wv == 0) ad(T0);
  if (wv == 1) ad(T1);
  __syncthreads();
  if (wv == 6) wr(T0);
  if (wv == 7) wr(T1);
  __syncthreads();
  if (wv == 2) ad(T0);
  if (wv == 3) ad(T1);
  __syncthreads();
  if (wv == 2) wr(T0);
  if (wv == 3) wr(T1);
  __syncthreads();
  if (wv == 0) ad(T0);
  if (wv == 1) ad(T1);
  __syncthreads();
  if (wv == 1) wr(T0);
  __syncthreads();
  if (wv == 0) {
    ad(T0);
    float* op = out + (size_t)bh * 4096;
#pragma unroll
    for (int i = 0; i < 8; ++i) {
      *(float4*)(op + (pr + i) * 64 + nr) =
          make_float4(acc[i][0], acc[i][1], acc[i][2], acc[i][3]);
      *(float4*)(op + (pr + i) * 64 + nr + 4) =
          make_float4(acc[i][4], acc[i][5], acc[i][6], acc[i][7]);
    }
  }
}

extern "C" void kernel_launch(void* const* d_in, const int* in_sizes, int n_in,
                              void* d_out, int out_size, void* d_ws, size_t ws_size,
                              hipStream_t stream) {
  const float* X = (const float*)d_in[0];
  const float* A = (const float*)d_in[1];
  const float* B = (const float*)d_in[2];
  // d_in[3] (C) and d_in[4] (block_len) unused by the collapsed math.
  float* out = (float*)d_out;

  const size_t smem = (size_t)(4096 + 2 * 4096) * 4;  // 48 KB
  mamba_fused<<<dim3(256), dim3(512), smem, stream>>>(X, A, B, out);
}